// Round 7
// baseline (1494.131 us; speedup 1.0000x reference)
//
#include <hip/hip_runtime.h>
#include <hip/hip_bf16.h>

typedef __hip_bfloat16 bf16;
typedef unsigned short u16;

#define N_NODES 100000
#define N_EDGES 1600000
#define F_IN 64
#define N_REL 8
#define N_GRAPH 256
#define N_HEAD 4
#define HC 128          // H*C
#define NBLK_SCAN 391   // ceil(100000/256)

__device__ __forceinline__ float lrelu(float x, float s) { return x >= 0.f ? x : s * x; }
__device__ __forceinline__ unsigned fenc(float f) {
  unsigned b = __float_as_uint(f);
  return (b & 0x80000000u) ? ~b : (b | 0x80000000u);
}
__device__ __forceinline__ float fdec(unsigned u) {
  float v = __uint_as_float((u & 0x80000000u) ? (u & 0x7fffffffu) : ~u);
  return fmaxf(fminf(v, 3e38f), -3e38f);
}
__device__ __forceinline__ float bf2f(bf16 v) { return __bfloat162float(v); }
__device__ __forceinline__ bf16 f2bf(float v) { return __float2bfloat16(v); }
__device__ __forceinline__ float lo_bf(unsigned u) { return __uint_as_float(u << 16); }
__device__ __forceinline__ float hi_bf(unsigned u) { return __uint_as_float(u & 0xFFFF0000u); }
// round-to-nearest-even f32 -> bf16 bits
__device__ __forceinline__ unsigned f2bfu(float v) {
  unsigned u = __float_as_uint(v);
  return (u + 0x7FFFu + ((u >> 16) & 1u)) >> 16;
}

// dtype-adaptive loads: BF=true -> bf16 array; BF=false -> fp32 array
template<bool BF> __device__ __forceinline__ float ldf(const void* p, size_t i) {
  if (BF) { u16 v = ((const u16*)p)[i]; return __uint_as_float(((unsigned)v) << 16); }
  else    { return ((const float*)p)[i]; }
}
template<bool BF> __device__ __forceinline__ float2 ldf2(const void* p, size_t i) {
  if (BF) { unsigned v = ((const unsigned*)p)[i]; return make_float2(lo_bf(v), hi_bf(v)); }
  else    { return ((const float2*)p)[i]; }
}

// ---- dtype probe ----
__global__ void k_probe(const u16* __restrict__ xr, int* __restrict__ flag) {
  int t = threadIdx.x;
  int c = 0;
  for (int i = t; i < 1024; i += 256) {
    unsigned e = (xr[i] >> 7) & 0xFFu;
    if (e >= 100u && e <= 140u) c++;
  }
  __shared__ int sc[256];
  sc[t] = c;
  __syncthreads();
  for (int s = 128; s; s >>= 1) { if (t < s) sc[t] += sc[t + s]; __syncthreads(); }
  if (t == 0) *flag = (sc[0] >= 800) ? 1 : 0;
}

// ---- GAT node logits: a_src/a_dst from x@W rowwise (h NOT stored; fp32 path packs xb) ----
template<bool BF>
__device__ __forceinline__ void gat_h_body(const void* x, const void* w, const void* att_s,
                                           const void* att_d, u16* __restrict__ xb,
                                           float* __restrict__ a_src, float* __restrict__ a_dst) {
  int n = blockIdx.x, j = threadIdx.x;
  __shared__ float xs[F_IN];
  if (j < F_IN) xs[j] = ldf<BF>(x, (size_t)n * F_IN + j);
  __syncthreads();
  if (!BF && j < F_IN) xb[(size_t)n * F_IN + j] = (u16)f2bfu(xs[j]);
  float acc = 0.f;
#pragma unroll
  for (int k = 0; k < F_IN; ++k) acc += xs[k] * ldf<BF>(w, (size_t)k * HC + j);
  float ps = acc * ldf<BF>(att_s, j);
  float pd = acc * ldf<BF>(att_d, j);
#pragma unroll
  for (int off = 16; off > 0; off >>= 1) {
    ps += __shfl_down(ps, off, 32);
    pd += __shfl_down(pd, off, 32);
  }
  if ((j & 31) == 0) {
    a_src[n * N_HEAD + (j >> 5)] = ps;
    a_dst[n * N_HEAD + (j >> 5)] = pd;
  }
}
__global__ void k_gat_h(const void* x, const void* w, const void* att_s, const void* att_d,
                        u16* xb, float* a_src, float* a_dst, const int* flag) {
  if (__builtin_amdgcn_readfirstlane(*flag)) gat_h_body<true>(x, w, att_s, att_d, xb, a_src, a_dst);
  else gat_h_body<false>(x, w, att_s, att_d, xb, a_src, a_dst);
}

// ---- CSR build: histogram ----
__global__ void k_hist(const int* __restrict__ ei, const int* __restrict__ etype,
                       int* __restrict__ deg, int* __restrict__ cnt) {
  int e = blockIdx.x * 256 + threadIdx.x;
  if (e >= N_EDGES) return;
  int d = ei[N_EDGES + e], t = etype[e];
  atomicAdd(&deg[d], 1);
  atomicAdd(&cnt[d * N_REL + t], 1);
}

// ---- 2-level exclusive scan ----
__global__ void k_scan_a(const int* __restrict__ deg, int* __restrict__ rowptr,
                         int* __restrict__ scanblk) {
  __shared__ int buf[256];
  int tid = threadIdx.x;
  int i = blockIdx.x * 256 + tid;
  int v = (i < N_NODES) ? deg[i] : 0;
  buf[tid] = v;
  __syncthreads();
  for (int st = 1; st < 256; st <<= 1) {
    int t = buf[tid];
    int a = (tid >= st) ? buf[tid - st] : 0;
    __syncthreads();
    buf[tid] = t + a;
    __syncthreads();
  }
  if (i < N_NODES) rowptr[i] = buf[tid] - v;
  if (tid == 255) scanblk[blockIdx.x] = buf[255];
}
__global__ void k_scan_b(int* __restrict__ scanblk) {
  __shared__ int buf[512];
  int tid = threadIdx.x;
  int v = (tid < NBLK_SCAN) ? scanblk[tid] : 0;
  buf[tid] = v;
  __syncthreads();
  for (int st = 1; st < 512; st <<= 1) {
    int t = buf[tid];
    int a = (tid >= st) ? buf[tid - st] : 0;
    __syncthreads();
    buf[tid] = t + a;
    __syncthreads();
  }
  if (tid < NBLK_SCAN) scanblk[tid] = buf[tid] - v;
}
__global__ void k_scan_c(int* __restrict__ rowptr, int* __restrict__ wp,
                         const int* __restrict__ scanblk) {
  int i = blockIdx.x * 256 + threadIdx.x;
  if (i < N_NODES) {
    int val = rowptr[i] + scanblk[blockIdx.x];
    rowptr[i] = val;
    wp[i] = val;
  } else if (i == N_NODES) {
    rowptr[N_NODES] = N_EDGES;
  }
}

// ---- scatter edges into CSR order; store logits + dst per pos ----
__global__ void k_scatter(const int* __restrict__ ei, const int* __restrict__ etype,
                          const float* __restrict__ a_src, const float* __restrict__ a_dst,
                          int* __restrict__ wp, unsigned* __restrict__ csr,
                          float4* __restrict__ p_logit, int* __restrict__ dstarr) {
  int e = blockIdx.x * 256 + threadIdx.x;
  if (e >= N_EDGES) return;
  int sn = ei[e], d = ei[N_EDGES + e], t = etype[e];
  int pos = atomicAdd(&wp[d], 1);
  csr[pos] = (unsigned)sn | ((unsigned)t << 20);
  dstarr[pos] = d;
  const float4 as = *(const float4*)&a_src[sn * 4];
  const float4 ad = *(const float4*)&a_dst[d * 4];
  float4 lg;
  lg.x = lrelu(as.x + ad.x, 0.2f);
  lg.y = lrelu(as.y + ad.y, 0.2f);
  lg.z = lrelu(as.z + ad.z, 0.2f);
  lg.w = lrelu(as.w + ad.w, 0.2f);
  p_logit[pos] = lg;
}

// ---- segment softmax stats: m, 1/s per (node, head); 16 nodes/block ----
__global__ void k_msum(const int* __restrict__ rowptr, const float* __restrict__ p_logit,
                       float* __restrict__ m_arr, float* __restrict__ si_arr) {
  int tid = threadIdx.x;
  int n = blockIdx.x * 16 + (tid >> 4);   // grid 6250, exact
  int l16 = tid & 15, head = l16 & 3, slot = l16 >> 2;
  int base = rowptr[n], deg = rowptr[n + 1] - base;
  float m = -1e30f;
  for (int i = slot; i < deg; i += 4) m = fmaxf(m, p_logit[(size_t)(base + i) * 4 + head]);
  m = fmaxf(m, __shfl_xor(m, 4, 64));
  m = fmaxf(m, __shfl_xor(m, 8, 64));
  float s = 0.f;
  for (int i = slot; i < deg; i += 4) s += __expf(p_logit[(size_t)(base + i) * 4 + head] - m);
  s += __shfl_xor(s, 4, 64);
  s += __shfl_xor(s, 8, 64);
  if (slot == 0) {
    m_arr[n * 4 + head] = m;
    si_arr[n * 4 + head] = (deg > 0) ? 1.f / s : 0.f;
  }
}

// ---- alpha in place: plog[pos] := exp(lg - m[dst]) * si[dst] ----
__global__ void k_alpha(const int* __restrict__ dstarr, const float* __restrict__ m_arr,
                        const float* __restrict__ si_arr, float4* __restrict__ plog4) {
  int p = blockIdx.x * 256 + threadIdx.x;
  if (p >= N_EDGES) return;
  int d = dstarr[p];
  float4 lg = plog4[p];
  const float4 m4 = *(const float4*)&m_arr[d * 4];
  const float4 s4 = *(const float4*)&si_arr[d * 4];
  float4 a;
  a.x = __expf(lg.x - m4.x) * s4.x;
  a.y = __expf(lg.y - m4.y) * s4.y;
  a.z = __expf(lg.z - m4.z) * s4.z;
  a.w = __expf(lg.w - m4.w) * s4.w;
  plog4[p] = a;
}

// ---- GAT aggregate via linearity: gather x rows (128B), per-head weighted x-sums,
//      then dense @W + bias + lrelu + dense1 + graph-max in block epilogue ----
template<bool BF>
__device__ __forceinline__ void gat_agg_body(const int* __restrict__ rowptr,
                                             const unsigned* __restrict__ csr,
                                             const float* __restrict__ alpha,
                                             const unsigned* __restrict__ xu, const void* gat_w,
                                             const void* gbias, const void* d1w, const void* d1b,
                                             const int* __restrict__ batch,
                                             unsigned* __restrict__ gmax, int* __restrict__ npg) {
  int tid = threadIdx.x;
  int wave = tid >> 6, l = tid & 63;
  int d = blockIdx.x * 4 + wave;  // grid 25000, exact
  __shared__ float u_lds[4][4][F_IN];  // [node][head][dim] f32, 4KB
  __shared__ float os[4][132];
  const float4* alpha4 = (const float4*)alpha;
  int base = rowptr[d];
  int deg = rowptr[d + 1] - base;
  int slot = l >> 5, cl = l & 31;   // lane covers x-dims 2cl, 2cl+1 of edge-slot `slot`
  float acc[4][2] = {{0.f,0.f},{0.f,0.f},{0.f,0.f},{0.f,0.f}};
  int i = slot;
  for (; i + 6 < deg; i += 8) {     // per slot: edges i, i+2, i+4, i+6 -> 4 x-loads in flight
    unsigned sp0 = csr[base + i],     sp1 = csr[base + i + 2];
    unsigned sp2 = csr[base + i + 4], sp3 = csr[base + i + 6];
    float4 a0 = alpha4[base + i],     a1 = alpha4[base + i + 2];
    float4 a2 = alpha4[base + i + 4], a3 = alpha4[base + i + 6];
    unsigned x0 = xu[(size_t)(sp0 & 0xFFFFF) * 32 + cl];
    unsigned x1 = xu[(size_t)(sp1 & 0xFFFFF) * 32 + cl];
    unsigned x2 = xu[(size_t)(sp2 & 0xFFFFF) * 32 + cl];
    unsigned x3 = xu[(size_t)(sp3 & 0xFFFFF) * 32 + cl];
    float x0l = lo_bf(x0), x0h = hi_bf(x0), x1l = lo_bf(x1), x1h = hi_bf(x1);
    float x2l = lo_bf(x2), x2h = hi_bf(x2), x3l = lo_bf(x3), x3h = hi_bf(x3);
    acc[0][0] += a0.x*x0l + a1.x*x1l + a2.x*x2l + a3.x*x3l;
    acc[0][1] += a0.x*x0h + a1.x*x1h + a2.x*x2h + a3.x*x3h;
    acc[1][0] += a0.y*x0l + a1.y*x1l + a2.y*x2l + a3.y*x3l;
    acc[1][1] += a0.y*x0h + a1.y*x1h + a2.y*x2h + a3.y*x3h;
    acc[2][0] += a0.z*x0l + a1.z*x1l + a2.z*x2l + a3.z*x3l;
    acc[2][1] += a0.z*x0h + a1.z*x1h + a2.z*x2h + a3.z*x3h;
    acc[3][0] += a0.w*x0l + a1.w*x1l + a2.w*x2l + a3.w*x3l;
    acc[3][1] += a0.w*x0h + a1.w*x1h + a2.w*x2h + a3.w*x3h;
  }
  for (; i < deg; i += 2) {
    unsigned sp = csr[base + i];
    float4 a0 = alpha4[base + i];
    unsigned xv = xu[(size_t)(sp & 0xFFFFF) * 32 + cl];
    float xl = lo_bf(xv), xh = hi_bf(xv);
    acc[0][0] += a0.x*xl; acc[0][1] += a0.x*xh;
    acc[1][0] += a0.y*xl; acc[1][1] += a0.y*xh;
    acc[2][0] += a0.z*xl; acc[2][1] += a0.z*xh;
    acc[3][0] += a0.w*xl; acc[3][1] += a0.w*xh;
  }
  // combine the two edge-slots
#pragma unroll
  for (int hh = 0; hh < 4; ++hh) {
    acc[hh][0] += __shfl_xor(acc[hh][0], 32, 64);
    acc[hh][1] += __shfl_xor(acc[hh][1], 32, 64);
  }
  if (slot == 0) {
#pragma unroll
    for (int hh = 0; hh < 4; ++hh) {
      u_lds[wave][hh][2 * cl]     = acc[hh][0];
      u_lds[wave][hh][2 * cl + 1] = acc[hh][1];
    }
  }
  __syncthreads();
  // epilogue A: os[node][j] = u[node][j>>5] . W[:,j], 2 adjacent outputs per thread
  {
    int node = tid >> 6, p = tid & 63;   // outputs 2p, 2p+1; head = p>>4
    int hh = p >> 4;
    float o0 = 0.f, o1 = 0.f;
#pragma unroll
    for (int k = 0; k < F_IN; ++k) {
      float2 wv = ldf2<BF>(gat_w, (size_t)k * 64 + p);
      float uv = u_lds[node][hh][k];
      o0 += uv * wv.x;
      o1 += uv * wv.y;
    }
    os[node][2 * p]     = lrelu(o0 + ldf<BF>(gbias, 2 * p), 0.01f);
    os[node][2 * p + 1] = lrelu(o1 + ldf<BF>(gbias, 2 * p + 1), 0.01f);
  }
  __syncthreads();
  if (tid < 64) {
    int node = tid >> 4, out = tid & 15;
    float a2 = ldf<BF>(d1b, out);
#pragma unroll
    for (int k = 0; k < HC; ++k) a2 += os[node][k] * ldf<BF>(d1w, (size_t)k * 16 + out);
    a2 = lrelu(a2, 0.01f);
    atomicMax(&gmax[batch[blockIdx.x * 4 + node] * 16 + out], fenc(a2));
  }
  if (tid < 4) atomicAdd(&npg[batch[blockIdx.x * 4 + tid]], 1);
}
__global__ void k_gat_agg(const int* rowptr, const unsigned* csr, const float* alpha,
                          const void* x_in, const u16* xb, const void* gat_w, const void* gbias,
                          const void* d1w, const void* d1b, const int* batch,
                          unsigned* gmax, int* npg, const int* flag) {
  if (__builtin_amdgcn_readfirstlane(*flag))
    gat_agg_body<true>(rowptr, csr, alpha, (const unsigned*)x_in, gat_w, gbias, d1w, d1b,
                       batch, gmax, npg);
  else
    gat_agg_body<false>(rowptr, csr, alpha, (const unsigned*)xb, gat_w, gbias, d1w, d1b,
                        batch, gmax, npg);
}

// ---- RGCN1: xw1[r,n,32] = x[n] @ rw1[r] ----
template<bool BF>
__device__ __forceinline__ void xw1_body(const void* x, const void* rw1, bf16* __restrict__ xw1) {
  __shared__ float xs[8][F_IN];
  int tid = threadIdx.x;
  int n0 = blockIdx.x * 8;
  for (int i = tid; i < 8 * F_IN; i += 256) {
    int nn = n0 + (i >> 6);
    xs[i >> 6][i & 63] = (nn < N_NODES) ? ldf<BF>(x, (size_t)nn * F_IN + (i & 63)) : 0.f;
  }
  __syncthreads();
  int nl = tid >> 5, c = tid & 31;
  int n = n0 + nl, r = blockIdx.y;
  float acc = 0.f;
#pragma unroll
  for (int k = 0; k < F_IN; ++k) acc += xs[nl][k] * ldf<BF>(rw1, (size_t)(r * F_IN + k) * 32 + c);
  if (n < N_NODES) xw1[((size_t)r * N_NODES + n) * 32 + c] = f2bf(acc);
}
__global__ void k_xw1(const void* x, const void* rw1, bf16* xw1, const int* flag) {
  if (__builtin_amdgcn_readfirstlane(*flag)) xw1_body<true>(x, rw1, xw1);
  else xw1_body<false>(x, rw1, xw1);
}

// ---- RGCN1 gather: 4 nodes/block, 64 lanes = 2 edge-slots x 32 ch ----
template<bool BF>
__device__ __forceinline__ void ragg1_body(const int* __restrict__ rowptr,
                                           const unsigned* __restrict__ csr,
                                           const int* __restrict__ cnt,
                                           const u16* __restrict__ xw, const void* x,
                                           const void* root1, const void* rb1,
                                           float* __restrict__ z1) {
  __shared__ float xs[4][F_IN];
  __shared__ float cinv[4][N_REL];
  int tid = threadIdx.x;
  int n0 = blockIdx.x * 4;  // grid 25000, exact
  {
    int nn = n0 + (tid >> 6);
    xs[tid >> 6][tid & 63] = ldf<BF>(x, (size_t)nn * F_IN + (tid & 63));
  }
  if (tid < 32) {
    int cv = cnt[(n0 + (tid >> 3)) * N_REL + (tid & 7)];
    cinv[tid >> 3][tid & 7] = (cv > 0) ? 1.f / (float)cv : 0.f;
  }
  __syncthreads();
  int wave = tid >> 6, l = tid & 63;
  int half = l >> 5, c = l & 31;
  int n = n0 + wave;
  int base = rowptr[n], deg = rowptr[n + 1] - base;
  float acc = 0.f;
  int i = half;
  for (; i + 2 < deg; i += 4) {
    unsigned sp0 = csr[base + i], sp1 = csr[base + i + 2];
    int t0 = sp0 >> 20, t1 = sp1 >> 20;
    u16 v0 = xw[((size_t)t0 * N_NODES + (sp0 & 0xFFFFF)) * 32 + c];
    u16 v1 = xw[((size_t)t1 * N_NODES + (sp1 & 0xFFFFF)) * 32 + c];
    acc += __uint_as_float(((unsigned)v0) << 16) * cinv[wave][t0];
    acc += __uint_as_float(((unsigned)v1) << 16) * cinv[wave][t1];
  }
  if (i < deg) {
    unsigned sp = csr[base + i];
    int t = sp >> 20;
    u16 v = xw[((size_t)t * N_NODES + (sp & 0xFFFFF)) * 32 + c];
    acc += __uint_as_float(((unsigned)v) << 16) * cinv[wave][t];
  }
  float r = 0.f;
#pragma unroll
  for (int kk = 0; kk < 32; ++kk) {
    int k = half * 32 + kk;
    r += xs[wave][k] * ldf<BF>(root1, (size_t)k * 32 + c);
  }
  float tot = acc + r;
  tot += __shfl_xor(tot, 32, 64);
  if (half == 0) z1[(size_t)n * 32 + c] = fmaxf(tot + ldf<BF>(rb1, c), 0.f);
}
__global__ void k_ragg1(const int* rowptr, const unsigned* csr, const int* cnt,
                        const bf16* xw1, const void* x, const void* root1, const void* rb1,
                        float* z1, const int* flag) {
  if (__builtin_amdgcn_readfirstlane(*flag))
    ragg1_body<true>(rowptr, csr, cnt, (const u16*)xw1, x, root1, rb1, z1);
  else
    ragg1_body<false>(rowptr, csr, cnt, (const u16*)xw1, x, root1, rb1, z1);
}

// ---- RGCN2: zw2[r,n,16] = z1[n] @ rw2[r] ----
template<bool BF>
__device__ __forceinline__ void zw2_body(const float* __restrict__ z1, const void* rw2,
                                         bf16* __restrict__ zw2) {
  __shared__ float zs[16][32];
  int tid = threadIdx.x;
  int n0 = blockIdx.x * 16;
  for (int i = tid; i < 16 * 32; i += 256) {
    int nn = n0 + (i >> 5);
    zs[i >> 5][i & 31] = (nn < N_NODES) ? z1[(size_t)nn * 32 + (i & 31)] : 0.f;
  }
  __syncthreads();
  int nl = tid >> 4, c = tid & 15;
  int n = n0 + nl, r = blockIdx.y;
  float acc = 0.f;
#pragma unroll
  for (int k = 0; k < 32; ++k) acc += zs[nl][k] * ldf<BF>(rw2, (size_t)(r * 32 + k) * 16 + c);
  if (n < N_NODES) zw2[((size_t)r * N_NODES + n) * 16 + c] = f2bf(acc);
}
__global__ void k_zw2(const float* z1, const void* rw2, bf16* zw2, const int* flag) {
  if (__builtin_amdgcn_readfirstlane(*flag)) zw2_body<true>(z1, rw2, zw2);
  else zw2_body<false>(z1, rw2, zw2);
}

// ---- RGCN2 gather: 4 nodes/block, 64 lanes = 4 edge-slots x 16 ch ----
template<bool BF>
__device__ __forceinline__ void ragg2_body(const int* __restrict__ rowptr,
                                           const unsigned* __restrict__ csr,
                                           const int* __restrict__ cnt,
                                           const u16* __restrict__ zw,
                                           const float* __restrict__ z1, const void* root2,
                                           const void* rb2, const int* __restrict__ batch,
                                           float* __restrict__ gsum) {
  __shared__ float zs[4][33];
  __shared__ float cinv[4][N_REL];
  int tid = threadIdx.x;
  int n0 = blockIdx.x * 4;  // grid 25000, exact
  if (tid < 128) {
    int nn = n0 + (tid >> 5);
    zs[tid >> 5][tid & 31] = z1[(size_t)nn * 32 + (tid & 31)];
  }
  if (tid < 32) {
    int cv = cnt[(n0 + (tid >> 3)) * N_REL + (tid & 7)];
    cinv[tid >> 3][tid & 7] = (cv > 0) ? 1.f / (float)cv : 0.f;
  }
  __syncthreads();
  int wave = tid >> 6, l = tid & 63;
  int q = l >> 4, c = l & 15;
  int n = n0 + wave;
  int base = rowptr[n], deg = rowptr[n + 1] - base;
  float acc = 0.f;
  int i = q;
  for (; i + 4 < deg; i += 8) {
    unsigned sp0 = csr[base + i], sp1 = csr[base + i + 4];
    int t0 = sp0 >> 20, t1 = sp1 >> 20;
    u16 v0 = zw[((size_t)t0 * N_NODES + (sp0 & 0xFFFFF)) * 16 + c];
    u16 v1 = zw[((size_t)t1 * N_NODES + (sp1 & 0xFFFFF)) * 16 + c];
    acc += __uint_as_float(((unsigned)v0) << 16) * cinv[wave][t0];
    acc += __uint_as_float(((unsigned)v1) << 16) * cinv[wave][t1];
  }
  if (i < deg) {
    unsigned sp = csr[base + i];
    int t = sp >> 20;
    u16 v = zw[((size_t)t * N_NODES + (sp & 0xFFFFF)) * 16 + c];
    acc += __uint_as_float(((unsigned)v) << 16) * cinv[wave][t];
  }
  float r = 0.f;
#pragma unroll
  for (int kk = 0; kk < 8; ++kk) {
    int k = q * 8 + kk;
    r += zs[wave][k] * ldf<BF>(root2, (size_t)k * 16 + c);
  }
  float tot = acc + r;
  tot += __shfl_xor(tot, 16, 64);
  tot += __shfl_xor(tot, 32, 64);
  if (q == 0) {
    float z2 = fmaxf(tot + ldf<BF>(rb2, c), 0.f);
    atomicAdd(&gsum[batch[n] * 16 + c], z2);
  }
}
__global__ void k_ragg2(const int* rowptr, const unsigned* csr, const int* cnt,
                        const bf16* zw2, const float* z1, const void* root2, const void* rb2,
                        const int* batch, float* gsum, const int* flag) {
  if (__builtin_amdgcn_readfirstlane(*flag))
    ragg2_body<true>(rowptr, csr, cnt, (const u16*)zw2, z1, root2, rb2, batch, gsum);
  else
    ragg2_body<false>(rowptr, csr, cnt, (const u16*)zw2, z1, root2, rb2, batch, gsum);
}

// ---- final ----
template<bool BF>
__device__ __forceinline__ void final_body(const unsigned* __restrict__ gmax,
                                           const float* __restrict__ gsum,
                                           const int* __restrict__ npg, const void* dw,
                                           const void* db, void* out) {
  int g = threadIdx.x;
  if (g >= N_GRAPH) return;
  float acc = ldf<BF>(db, 0);
  int np = npg[g]; if (np < 1) np = 1;
  float inv = 1.f / (float)np;
#pragma unroll
  for (int c = 0; c < 16; ++c) {
    acc += fdec(gmax[g * 16 + c]) * ldf<BF>(dw, c);
    acc += (gsum[g * 16 + c] * inv) * ldf<BF>(dw, 16 + c);
  }
  if (BF) ((bf16*)out)[g] = f2bf(acc);
  else ((float*)out)[g] = acc;
}
__global__ void k_final(const unsigned* gmax, const float* gsum, const int* npg,
                        const void* dw, const void* db, void* out, const int* flag) {
  if (__builtin_amdgcn_readfirstlane(*flag)) final_body<true>(gmax, gsum, npg, dw, db, out);
  else final_body<false>(gmax, gsum, npg, dw, db, out);
}

extern "C" void kernel_launch(void* const* d_in, const int* in_sizes, int n_in,
                              void* d_out, int out_size, void* d_ws, size_t ws_size,
                              hipStream_t stream) {
  const void* x        = d_in[0];
  const int*  ei       = (const int*)d_in[1];
  const int*  etype    = (const int*)d_in[2];
  const int*  batch    = (const int*)d_in[3];
  const void* gat_w    = d_in[4];
  const void* att_src  = d_in[5];
  const void* att_dst  = d_in[6];
  const void* gat_bias = d_in[7];
  const void* d1w      = d_in[8];
  const void* d1b      = d_in[9];
  const void* rw1      = d_in[10];
  const void* root1    = d_in[11];
  const void* rb1      = d_in[12];
  const void* rw2      = d_in[13];
  const void* root2    = d_in[14];
  const void* rb2      = d_in[15];
  const void* dw       = d_in[16];
  const void* db       = d_in[17];

  // ---- workspace layout (~97 MB, phase-aliased region A) ----
  char* ws = (char*)d_ws;
  const size_t o_plog  = 25600000;    // f32  E*4   (25.6MB)   — GAT (logits -> alpha in place)
  const size_t o_xw1   = 0;           // bf16 R*N*32 (51.2MB)  — RGCN1 (overlays dead region 0..25.6 + plog)
  const size_t o_zw2   = 0;           // bf16 R*N*16 (25.6MB)  — RGCN2, overlays xw1 (dead)
  const size_t o_asrc  = 51200000;    // f32 N*4 (1.6MB) -> reused as m_arr
  const size_t o_adst  = 52800000;    // f32 N*4 (1.6MB) -> reused as si_arr
  const size_t o_deg   = 54400000;    // i32 N   (0.4MB)
  const size_t o_rowp  = 54800000;    // i32 N+1
  const size_t o_wp    = 55200016;    // i32 N
  const size_t o_cnt   = 55600032;    // i32 N*8 (3.2MB)
  const size_t o_csr   = 58800032;    // u32 E   (6.4MB)
  const size_t o_z1    = 65200032;    // f32 N*32 (12.8MB)
  const size_t o_sblk  = 78000032;    // i32 NBLK_SCAN
  const size_t o_gmax  = 78001600;    // u32 G*16
  const size_t o_gsum  = 78017984;    // f32 G*16
  const size_t o_npg   = 78034368;    // i32 G
  const size_t o_flag  = 78035392;    // i32
  const size_t o_dst   = 78035400;    // i32 E (6.4MB) — dst per CSR pos (GAT phase)
  const size_t o_xb    = 84435400;    // u16 N*64 (12.8MB) — bf16-packed x (fp32 path only)
  const size_t total   = 97235400;
  if (ws_size < total) return;

  float*    plog   = (float*)(ws + o_plog);
  bf16*     xw1    = (bf16*)(ws + o_xw1);
  bf16*     zw2    = (bf16*)(ws + o_zw2);
  float*    a_src  = (float*)(ws + o_asrc);
  float*    a_dst  = (float*)(ws + o_adst);
  int*      deg    = (int*)(ws + o_deg);
  int*      rowptr = (int*)(ws + o_rowp);
  int*      wp     = (int*)(ws + o_wp);
  int*      cnt    = (int*)(ws + o_cnt);
  unsigned* csr    = (unsigned*)(ws + o_csr);
  float*    z1     = (float*)(ws + o_z1);
  int*      sblk   = (int*)(ws + o_sblk);
  unsigned* gmax   = (unsigned*)(ws + o_gmax);
  float*    gsum   = (float*)(ws + o_gsum);
  int*      npg    = (int*)(ws + o_npg);
  int*      flag   = (int*)(ws + o_flag);
  int*      dstarr = (int*)(ws + o_dst);
  u16*      xb     = (u16*)(ws + o_xb);

  // dtype probe
  k_probe<<<1, 256, 0, stream>>>((const u16*)x, flag);

  // zero-init
  hipMemsetAsync(ws + o_deg, 0, o_csr - o_deg, stream);
  hipMemsetAsync(ws + o_gmax, 0, 33792, stream);

  // attention logits per node (h not materialized; fp32 path packs xb)
  k_gat_h<<<N_NODES, 128, 0, stream>>>(x, gat_w, att_src, att_dst, xb, a_src, a_dst, flag);

  // CSR build
  k_hist<<<(N_EDGES + 255) / 256, 256, 0, stream>>>(ei, etype, deg, cnt);
  k_scan_a<<<NBLK_SCAN, 256, 0, stream>>>(deg, rowptr, sblk);
  k_scan_b<<<1, 512, 0, stream>>>(sblk);
  k_scan_c<<<NBLK_SCAN, 256, 0, stream>>>(rowptr, wp, sblk);
  k_scatter<<<(N_EDGES + 255) / 256, 256, 0, stream>>>(ei, etype, a_src, a_dst, wp, csr,
                                                       (float4*)plog, dstarr);

  // softmax stats (a_src/a_dst reused as m/si) + alpha in place
  k_msum<<<N_NODES / 16, 256, 0, stream>>>(rowptr, plog, a_src, a_dst);
  k_alpha<<<(N_EDGES + 255) / 256, 256, 0, stream>>>(dstarr, a_src, a_dst, (float4*)plog);

  // GAT aggregate: x-space gather (linearity), dense W epilogue
  k_gat_agg<<<N_NODES / 4, 256, 0, stream>>>(rowptr, csr, plog, x, xb, gat_w, gat_bias,
                                             d1w, d1b, batch, gmax, npg, flag);

  // RGCN layer 1 (xw1 overlays GAT scratch — GAT phase done)
  k_xw1<<<dim3((N_NODES + 7) / 8, N_REL), 256, 0, stream>>>(x, rw1, xw1, flag);
  k_ragg1<<<N_NODES / 4, 256, 0, stream>>>(rowptr, csr, cnt, xw1, x, root1, rb1, z1, flag);

  // RGCN layer 2 (zw2 overlays xw1)
  k_zw2<<<dim3((N_NODES + 15) / 16, N_REL), 256, 0, stream>>>(z1, rw2, zw2, flag);
  k_ragg2<<<N_NODES / 4, 256, 0, stream>>>(rowptr, csr, cnt, zw2, z1, root2, rb2,
                                           batch, gsum, flag);

  // fuse
  k_final<<<1, 256, 0, stream>>>(gmax, gsum, npg, dw, db, d_out, flag);
}

// Round 8
// 1230.278 us; speedup vs baseline: 1.2145x; 1.2145x over previous
//
#include <hip/hip_runtime.h>
#include <hip/hip_bf16.h>

typedef __hip_bfloat16 bf16;
typedef unsigned short u16;

#define N_NODES 100000
#define N_EDGES 1600000
#define F_IN 64
#define N_REL 8
#define N_GRAPH 256
#define N_HEAD 4
#define HC 128          // H*C
#define NBLK_SCAN 391   // ceil(100000/256)

__device__ __forceinline__ float lrelu(float x, float s) { return x >= 0.f ? x : s * x; }
__device__ __forceinline__ unsigned fenc(float f) {
  unsigned b = __float_as_uint(f);
  return (b & 0x80000000u) ? ~b : (b | 0x80000000u);
}
__device__ __forceinline__ float fdec(unsigned u) {
  float v = __uint_as_float((u & 0x80000000u) ? (u & 0x7fffffffu) : ~u);
  return fmaxf(fminf(v, 3e38f), -3e38f);
}
__device__ __forceinline__ float bf2f(bf16 v) { return __bfloat162float(v); }
__device__ __forceinline__ bf16 f2bf(float v) { return __float2bfloat16(v); }
__device__ __forceinline__ float lo_bf(unsigned u) { return __uint_as_float(u << 16); }
__device__ __forceinline__ float hi_bf(unsigned u) { return __uint_as_float(u & 0xFFFF0000u); }
__device__ __forceinline__ unsigned f2bfu(float v) {
  unsigned u = __float_as_uint(v);
  return (u + 0x7FFFu + ((u >> 16) & 1u)) >> 16;
}

// dtype-adaptive loads: BF=true -> bf16 array; BF=false -> fp32 array
template<bool BF> __device__ __forceinline__ float ldf(const void* p, size_t i) {
  if (BF) { u16 v = ((const u16*)p)[i]; return __uint_as_float(((unsigned)v) << 16); }
  else    { return ((const float*)p)[i]; }
}
template<bool BF> __device__ __forceinline__ float2 ldf2(const void* p, size_t i) {
  if (BF) { unsigned v = ((const unsigned*)p)[i]; return make_float2(lo_bf(v), hi_bf(v)); }
  else    { return ((const float2*)p)[i]; }
}

// ---- dtype probe ----
__global__ void k_probe(const u16* __restrict__ xr, int* __restrict__ flag) {
  int t = threadIdx.x;
  int c = 0;
  for (int i = t; i < 1024; i += 256) {
    unsigned e = (xr[i] >> 7) & 0xFFu;
    if (e >= 100u && e <= 140u) c++;
  }
  __shared__ int sc[256];
  sc[t] = c;
  __syncthreads();
  for (int s = 128; s; s >>= 1) { if (t < s) sc[t] += sc[t + s]; __syncthreads(); }
  if (t == 0) *flag = (sc[0] >= 800) ? 1 : 0;
}

// ---- GAT node transform body (1 node / 128 threads; proven shape) ----
template<bool BF>
__device__ __forceinline__ void gat_h_body(const void* x, const void* w, const void* att_s,
                                           const void* att_d, u16* __restrict__ h,
                                           float* __restrict__ a_src, float* __restrict__ a_dst,
                                           int n, float* xs) {
  int j = threadIdx.x;
  if (j < F_IN) xs[j] = ldf<BF>(x, (size_t)n * F_IN + j);
  __syncthreads();
  float acc = 0.f;
#pragma unroll
  for (int k = 0; k < F_IN; ++k) acc += xs[k] * ldf<BF>(w, (size_t)k * HC + j);
  h[(size_t)n * HC + j] = (u16)f2bfu(acc);
  float ps = acc * ldf<BF>(att_s, j);
  float pd = acc * ldf<BF>(att_d, j);
#pragma unroll
  for (int off = 16; off > 0; off >>= 1) {
    ps += __shfl_down(ps, off, 32);
    pd += __shfl_down(pd, off, 32);
  }
  if ((j & 31) == 0) {
    a_src[n * N_HEAD + (j >> 5)] = ps;
    a_dst[n * N_HEAD + (j >> 5)] = pd;
  }
}

// ---- merged: gat_h (blocks 0..99999) + hist (blocks 100000..112499) ----
__global__ void k_gath_hist(const void* x, const void* w, const void* att_s, const void* att_d,
                            u16* h, float* a_src, float* a_dst,
                            const int* __restrict__ ei, const int* __restrict__ etype,
                            int* __restrict__ deg, int* __restrict__ cnt, const int* flag) {
  __shared__ float xs[F_IN];
  if (blockIdx.x < N_NODES) {
    if (__builtin_amdgcn_readfirstlane(*flag))
      gat_h_body<true>(x, w, att_s, att_d, h, a_src, a_dst, blockIdx.x, xs);
    else
      gat_h_body<false>(x, w, att_s, att_d, h, a_src, a_dst, blockIdx.x, xs);
  } else {
    int e = (blockIdx.x - N_NODES) * 128 + threadIdx.x;
    if (e < N_EDGES) {
      int d = ei[N_EDGES + e], t = etype[e];
      atomicAdd(&deg[d], 1);
      atomicAdd(&cnt[d * N_REL + t], 1);
    }
  }
}

// ---- 2-level exclusive scan ----
__global__ void k_scan_a(const int* __restrict__ deg, int* __restrict__ rowptr,
                         int* __restrict__ scanblk) {
  __shared__ int buf[256];
  int tid = threadIdx.x;
  int i = blockIdx.x * 256 + tid;
  int v = (i < N_NODES) ? deg[i] : 0;
  buf[tid] = v;
  __syncthreads();
  for (int st = 1; st < 256; st <<= 1) {
    int t = buf[tid];
    int a = (tid >= st) ? buf[tid - st] : 0;
    __syncthreads();
    buf[tid] = t + a;
    __syncthreads();
  }
  if (i < N_NODES) rowptr[i] = buf[tid] - v;
  if (tid == 255) scanblk[blockIdx.x] = buf[255];
}
__global__ void k_scan_b(int* __restrict__ scanblk) {
  __shared__ int buf[512];
  int tid = threadIdx.x;
  int v = (tid < NBLK_SCAN) ? scanblk[tid] : 0;
  buf[tid] = v;
  __syncthreads();
  for (int st = 1; st < 512; st <<= 1) {
    int t = buf[tid];
    int a = (tid >= st) ? buf[tid - st] : 0;
    __syncthreads();
    buf[tid] = t + a;
    __syncthreads();
  }
  if (tid < NBLK_SCAN) scanblk[tid] = buf[tid] - v;
}
__global__ void k_scan_c(int* __restrict__ rowptr, int* __restrict__ wp,
                         const int* __restrict__ scanblk) {
  int i = blockIdx.x * 256 + threadIdx.x;
  if (i < N_NODES) {
    int val = rowptr[i] + scanblk[blockIdx.x];
    rowptr[i] = val;
    wp[i] = val;
  } else if (i == N_NODES) {
    rowptr[N_NODES] = N_EDGES;
  }
}

// ---- scatter edges into CSR order; store logits + dst per pos ----
__global__ void k_scatter(const int* __restrict__ ei, const int* __restrict__ etype,
                          const float* __restrict__ a_src, const float* __restrict__ a_dst,
                          int* __restrict__ wp, unsigned* __restrict__ csr,
                          float4* __restrict__ p_logit, int* __restrict__ dstarr) {
  int e = blockIdx.x * 256 + threadIdx.x;
  if (e >= N_EDGES) return;
  int sn = ei[e], d = ei[N_EDGES + e], t = etype[e];
  int pos = atomicAdd(&wp[d], 1);
  csr[pos] = (unsigned)sn | ((unsigned)t << 20);
  dstarr[pos] = d;
  const float4 as = *(const float4*)&a_src[sn * 4];
  const float4 ad = *(const float4*)&a_dst[d * 4];
  float4 lg;
  lg.x = lrelu(as.x + ad.x, 0.2f);
  lg.y = lrelu(as.y + ad.y, 0.2f);
  lg.z = lrelu(as.z + ad.z, 0.2f);
  lg.w = lrelu(as.w + ad.w, 0.2f);
  p_logit[pos] = lg;
}

// ---- segment softmax stats: m, 1/s per (node, head); 16 nodes/block ----
__global__ void k_msum(const int* __restrict__ rowptr, const float* __restrict__ p_logit,
                       float* __restrict__ m_arr, float* __restrict__ si_arr) {
  int tid = threadIdx.x;
  int n = blockIdx.x * 16 + (tid >> 4);   // grid 6250, exact
  int l16 = tid & 15, head = l16 & 3, slot = l16 >> 2;
  int base = rowptr[n], deg = rowptr[n + 1] - base;
  float m = -1e30f;
  for (int i = slot; i < deg; i += 4) m = fmaxf(m, p_logit[(size_t)(base + i) * 4 + head]);
  m = fmaxf(m, __shfl_xor(m, 4, 64));
  m = fmaxf(m, __shfl_xor(m, 8, 64));
  float s = 0.f;
  for (int i = slot; i < deg; i += 4) s += __expf(p_logit[(size_t)(base + i) * 4 + head] - m);
  s += __shfl_xor(s, 4, 64);
  s += __shfl_xor(s, 8, 64);
  if (slot == 0) {
    m_arr[n * 4 + head] = m;
    si_arr[n * 4 + head] = (deg > 0) ? 1.f / s : 0.f;
  }
}

// ---- alpha in place: plog[pos] := exp(lg - m[dst]) * si[dst] ----
__global__ void k_alpha(const int* __restrict__ dstarr, const float* __restrict__ m_arr,
                        const float* __restrict__ si_arr, float4* __restrict__ plog4) {
  int p = blockIdx.x * 256 + threadIdx.x;
  if (p >= N_EDGES) return;
  int d = dstarr[p];
  float4 lg = plog4[p];
  const float4 m4 = *(const float4*)&m_arr[d * 4];
  const float4 s4 = *(const float4*)&si_arr[d * 4];
  float4 a;
  a.x = __expf(lg.x - m4.x) * s4.x;
  a.y = __expf(lg.y - m4.y) * s4.y;
  a.z = __expf(lg.z - m4.z) * s4.z;
  a.w = __expf(lg.w - m4.w) * s4.w;
  plog4[p] = a;
}

// ---- GAT aggregate body (round-6 proven): 4 nodes/block, uint2 loads, 8 in flight ----
template<bool BF>
__device__ __forceinline__ void gat_agg_body(const int* __restrict__ rowptr,
                                             const unsigned* __restrict__ csr,
                                             const float* __restrict__ alpha,
                                             const uint2* __restrict__ hu2, const void* gbias,
                                             const void* d1w, const void* d1b,
                                             const int* __restrict__ batch,
                                             unsigned* __restrict__ gmax, int* __restrict__ npg,
                                             float (*os)[132], int bid) {
  int tid = threadIdx.x;
  int wave = tid >> 6, l = tid & 63;
  int d = bid * 4 + wave;
  int base = rowptr[d];
  int deg = rowptr[d + 1] - base;
  int slot = l >> 5, cl = l & 31;   // lane covers channels 4cl..4cl+3 of edge-slot `slot`
  int head = cl >> 3;
  float a0 = 0.f, a1 = 0.f, a2 = 0.f, a3 = 0.f;
  int i = slot;
  for (; i + 6 < deg; i += 8) {
    unsigned sp0 = csr[base + i],     sp1 = csr[base + i + 2];
    unsigned sp2 = csr[base + i + 4], sp3 = csr[base + i + 6];
    float av0 = alpha[(size_t)(base + i) * 4 + head];
    float av1 = alpha[(size_t)(base + i + 2) * 4 + head];
    float av2 = alpha[(size_t)(base + i + 4) * 4 + head];
    float av3 = alpha[(size_t)(base + i + 6) * 4 + head];
    uint2 h0 = hu2[(size_t)(sp0 & 0xFFFFF) * 32 + cl];
    uint2 h1 = hu2[(size_t)(sp1 & 0xFFFFF) * 32 + cl];
    uint2 h2 = hu2[(size_t)(sp2 & 0xFFFFF) * 32 + cl];
    uint2 h3 = hu2[(size_t)(sp3 & 0xFFFFF) * 32 + cl];
    a0 += lo_bf(h0.x) * av0 + lo_bf(h1.x) * av1 + lo_bf(h2.x) * av2 + lo_bf(h3.x) * av3;
    a1 += hi_bf(h0.x) * av0 + hi_bf(h1.x) * av1 + hi_bf(h2.x) * av2 + hi_bf(h3.x) * av3;
    a2 += lo_bf(h0.y) * av0 + lo_bf(h1.y) * av1 + lo_bf(h2.y) * av2 + lo_bf(h3.y) * av3;
    a3 += hi_bf(h0.y) * av0 + hi_bf(h1.y) * av1 + hi_bf(h2.y) * av2 + hi_bf(h3.y) * av3;
  }
  for (; i < deg; i += 2) {
    unsigned sp = csr[base + i];
    float av = alpha[(size_t)(base + i) * 4 + head];
    uint2 hv = hu2[(size_t)(sp & 0xFFFFF) * 32 + cl];
    a0 += lo_bf(hv.x) * av;
    a1 += hi_bf(hv.x) * av;
    a2 += lo_bf(hv.y) * av;
    a3 += hi_bf(hv.y) * av;
  }
  a0 += __shfl_xor(a0, 32, 64);
  a1 += __shfl_xor(a1, 32, 64);
  a2 += __shfl_xor(a2, 32, 64);
  a3 += __shfl_xor(a3, 32, 64);
  if (slot == 0) {
    os[wave][4 * cl + 0] = lrelu(a0 + ldf<BF>(gbias, 4 * cl + 0), 0.01f);
    os[wave][4 * cl + 1] = lrelu(a1 + ldf<BF>(gbias, 4 * cl + 1), 0.01f);
    os[wave][4 * cl + 2] = lrelu(a2 + ldf<BF>(gbias, 4 * cl + 2), 0.01f);
    os[wave][4 * cl + 3] = lrelu(a3 + ldf<BF>(gbias, 4 * cl + 3), 0.01f);
  }
  __syncthreads();
  if (tid < 64) {
    int node = tid >> 4, out = tid & 15;
    float acc = ldf<BF>(d1b, out);
#pragma unroll
    for (int k = 0; k < HC; ++k) acc += os[node][k] * ldf<BF>(d1w, (size_t)k * 16 + out);
    acc = lrelu(acc, 0.01f);
    atomicMax(&gmax[batch[bid * 4 + node] * 16 + out], fenc(acc));
  }
  if (tid < 4) atomicAdd(&npg[batch[bid * 4 + tid]], 1);
}

// ---- RGCN1 transform body: 8 nodes x 1 relation per block ----
template<bool BF>
__device__ __forceinline__ void xw1_body(const void* x, const void* rw1, bf16* __restrict__ xw1,
                                         int n0, int r, float (*xs)[F_IN]) {
  int tid = threadIdx.x;
  for (int i = tid; i < 8 * F_IN; i += 256) {
    int nn = n0 + (i >> 6);
    xs[i >> 6][i & 63] = (nn < N_NODES) ? ldf<BF>(x, (size_t)nn * F_IN + (i & 63)) : 0.f;
  }
  __syncthreads();
  int nl = tid >> 5, c = tid & 31;
  int n = n0 + nl;
  float acc = 0.f;
#pragma unroll
  for (int k = 0; k < F_IN; ++k) acc += xs[nl][k] * ldf<BF>(rw1, (size_t)(r * F_IN + k) * 32 + c);
  if (n < N_NODES) xw1[((size_t)r * N_NODES + n) * 32 + c] = f2bf(acc);
}

// ---- merged: gat_agg (blocks 0..24999) + xw1 (blocks 25000..124999) ----
__global__ void k_aggxw1(const int* rowptr, const unsigned* csr, const float* alpha,
                         const u16* h, const void* gbias, const void* d1w, const void* d1b,
                         const int* batch, unsigned* gmax, int* npg,
                         const void* x, const void* rw1, bf16* xw1, const int* flag) {
  __shared__ float sh[544];   // union: os[4][132]=528 | xs[8][64]=512
  int bf = __builtin_amdgcn_readfirstlane(*flag);
  if (blockIdx.x < 25000) {
    if (bf) gat_agg_body<true>(rowptr, csr, alpha, (const uint2*)h, gbias, d1w, d1b,
                               batch, gmax, npg, (float(*)[132])sh, blockIdx.x);
    else    gat_agg_body<false>(rowptr, csr, alpha, (const uint2*)h, gbias, d1w, d1b,
                                batch, gmax, npg, (float(*)[132])sh, blockIdx.x);
  } else {
    int nb = blockIdx.x - 25000;
    int n0 = (nb % 12500) * 8;
    int r  = nb / 12500;
    if (bf) xw1_body<true>(x, rw1, xw1, n0, r, (float(*)[F_IN])sh);
    else    xw1_body<false>(x, rw1, xw1, n0, r, (float(*)[F_IN])sh);
  }
}

// ---- RGCN1 gather: 4 nodes/block, 4 edge-slots x 16 lanes x 2ch (u32), 8 in flight ----
template<bool BF>
__device__ __forceinline__ void ragg1_body(const int* __restrict__ rowptr,
                                           const unsigned* __restrict__ csr,
                                           const int* __restrict__ cnt,
                                           const unsigned* __restrict__ xw, const void* x,
                                           const void* root1, const void* rb1,
                                           float* __restrict__ z1) {
  __shared__ float xs[4][F_IN];
  __shared__ float cinv[4][N_REL];
  int tid = threadIdx.x;
  int n0 = blockIdx.x * 4;  // grid 25000, exact
  {
    int nn = n0 + (tid >> 6);
    xs[tid >> 6][tid & 63] = ldf<BF>(x, (size_t)nn * F_IN + (tid & 63));
  }
  if (tid < 32) {
    int cv = cnt[(n0 + (tid >> 3)) * N_REL + (tid & 7)];
    cinv[tid >> 3][tid & 7] = (cv > 0) ? 1.f / (float)cv : 0.f;
  }
  __syncthreads();
  int wave = tid >> 6, l = tid & 63;
  int slot = l >> 4, cl = l & 15;   // channels 2cl, 2cl+1
  int n = n0 + wave;
  int base = rowptr[n], deg = rowptr[n + 1] - base;
  float a0 = 0.f, a1 = 0.f;
  int i = slot;
  for (; i + 4 < deg; i += 8) {
    unsigned sp0 = csr[base + i], sp1 = csr[base + i + 4];
    int t0 = sp0 >> 20, t1 = sp1 >> 20;
    unsigned v0 = xw[((size_t)t0 * N_NODES + (sp0 & 0xFFFFF)) * 16 + cl];
    unsigned v1 = xw[((size_t)t1 * N_NODES + (sp1 & 0xFFFFF)) * 16 + cl];
    float c0 = cinv[wave][t0], c1 = cinv[wave][t1];
    a0 += lo_bf(v0) * c0 + lo_bf(v1) * c1;
    a1 += hi_bf(v0) * c0 + hi_bf(v1) * c1;
  }
  if (i < deg) {
    unsigned sp = csr[base + i];
    int t = sp >> 20;
    unsigned v = xw[((size_t)t * N_NODES + (sp & 0xFFFFF)) * 16 + cl];
    float c0 = cinv[wave][t];
    a0 += lo_bf(v) * c0;
    a1 += hi_bf(v) * c0;
  }
  // root part: slot covers k in [slot*16, slot*16+16)
#pragma unroll
  for (int kk = 0; kk < 16; ++kk) {
    int k = slot * 16 + kk;
    float xv = xs[wave][k];
    float2 wv = ldf2<BF>(root1, (size_t)k * 16 + cl);
    a0 += xv * wv.x;
    a1 += xv * wv.y;
  }
  a0 += __shfl_xor(a0, 16, 64); a0 += __shfl_xor(a0, 32, 64);
  a1 += __shfl_xor(a1, 16, 64); a1 += __shfl_xor(a1, 32, 64);
  if (slot == 0) {
    z1[(size_t)n * 32 + 2 * cl]     = fmaxf(a0 + ldf<BF>(rb1, 2 * cl), 0.f);
    z1[(size_t)n * 32 + 2 * cl + 1] = fmaxf(a1 + ldf<BF>(rb1, 2 * cl + 1), 0.f);
  }
}
__global__ void k_ragg1(const int* rowptr, const unsigned* csr, const int* cnt,
                        const bf16* xw1, const void* x, const void* root1, const void* rb1,
                        float* z1, const int* flag) {
  if (__builtin_amdgcn_readfirstlane(*flag))
    ragg1_body<true>(rowptr, csr, cnt, (const unsigned*)xw1, x, root1, rb1, z1);
  else
    ragg1_body<false>(rowptr, csr, cnt, (const unsigned*)xw1, x, root1, rb1, z1);
}

// ---- RGCN2: zw2[r,n,16] = z1[n] @ rw2[r] ----
template<bool BF>
__device__ __forceinline__ void zw2_body(const float* __restrict__ z1, const void* rw2,
                                         bf16* __restrict__ zw2) {
  __shared__ float zs[16][32];
  int tid = threadIdx.x;
  int n0 = blockIdx.x * 16;
  for (int i = tid; i < 16 * 32; i += 256) {
    int nn = n0 + (i >> 5);
    zs[i >> 5][i & 31] = (nn < N_NODES) ? z1[(size_t)nn * 32 + (i & 31)] : 0.f;
  }
  __syncthreads();
  int nl = tid >> 4, c = tid & 15;
  int n = n0 + nl, r = blockIdx.y;
  float acc = 0.f;
#pragma unroll
  for (int k = 0; k < 32; ++k) acc += zs[nl][k] * ldf<BF>(rw2, (size_t)(r * 32 + k) * 16 + c);
  if (n < N_NODES) zw2[((size_t)r * N_NODES + n) * 16 + c] = f2bf(acc);
}
__global__ void k_zw2(const float* z1, const void* rw2, bf16* zw2, const int* flag) {
  if (__builtin_amdgcn_readfirstlane(*flag)) zw2_body<true>(z1, rw2, zw2);
  else zw2_body<false>(z1, rw2, zw2);
}

// ---- RGCN2 gather: 4 nodes/block, 8 edge-slots x 8 lanes x 2ch (u32), 16 in flight ----
template<bool BF>
__device__ __forceinline__ void ragg2_body(const int* __restrict__ rowptr,
                                           const unsigned* __restrict__ csr,
                                           const int* __restrict__ cnt,
                                           const unsigned* __restrict__ zw,
                                           const float* __restrict__ z1, const void* root2,
                                           const void* rb2, const int* __restrict__ batch,
                                           float* __restrict__ gsum) {
  __shared__ float zs[4][33];
  __shared__ float cinv[4][N_REL];
  int tid = threadIdx.x;
  int n0 = blockIdx.x * 4;  // grid 25000, exact
  if (tid < 128) {
    int nn = n0 + (tid >> 5);
    zs[tid >> 5][tid & 31] = z1[(size_t)nn * 32 + (tid & 31)];
  }
  if (tid < 32) {
    int cv = cnt[(n0 + (tid >> 3)) * N_REL + (tid & 7)];
    cinv[tid >> 3][tid & 7] = (cv > 0) ? 1.f / (float)cv : 0.f;
  }
  __syncthreads();
  int wave = tid >> 6, l = tid & 63;
  int slot = l >> 3, cl = l & 7;   // channels 2cl, 2cl+1 of 16
  int n = n0 + wave;
  int base = rowptr[n], deg = rowptr[n + 1] - base;
  float a0 = 0.f, a1 = 0.f;
  int i = slot;
  for (; i + 8 < deg; i += 16) {
    unsigned sp0 = csr[base + i], sp1 = csr[base + i + 8];
    int t0 = sp0 >> 20, t1 = sp1 >> 20;
    unsigned v0 = zw[((size_t)t0 * N_NODES + (sp0 & 0xFFFFF)) * 8 + cl];
    unsigned v1 = zw[((size_t)t1 * N_NODES + (sp1 & 0xFFFFF)) * 8 + cl];
    float c0 = cinv[wave][t0], c1 = cinv[wave][t1];
    a0 += lo_bf(v0) * c0 + lo_bf(v1) * c1;
    a1 += hi_bf(v0) * c0 + hi_bf(v1) * c1;
  }
  if (i < deg) {
    unsigned sp = csr[base + i];
    int t = sp >> 20;
    unsigned v = zw[((size_t)t * N_NODES + (sp & 0xFFFFF)) * 8 + cl];
    float c0 = cinv[wave][t];
    a0 += lo_bf(v) * c0;
    a1 += hi_bf(v) * c0;
  }
  // root part: slot covers k in [slot*4, slot*4+4)
#pragma unroll
  for (int kk = 0; kk < 4; ++kk) {
    int k = slot * 4 + kk;
    float zv = zs[wave][k];
    float2 wv = ldf2<BF>(root2, (size_t)k * 8 + cl);
    a0 += zv * wv.x;
    a1 += zv * wv.y;
  }
  a0 += __shfl_xor(a0, 8, 64); a0 += __shfl_xor(a0, 16, 64); a0 += __shfl_xor(a0, 32, 64);
  a1 += __shfl_xor(a1, 8, 64); a1 += __shfl_xor(a1, 16, 64); a1 += __shfl_xor(a1, 32, 64);
  if (slot == 0) {
    float z2a = fmaxf(a0 + ldf<BF>(rb2, 2 * cl), 0.f);
    float z2b = fmaxf(a1 + ldf<BF>(rb2, 2 * cl + 1), 0.f);
    int g = batch[n];
    atomicAdd(&gsum[g * 16 + 2 * cl], z2a);
    atomicAdd(&gsum[g * 16 + 2 * cl + 1], z2b);
  }
}
__global__ void k_ragg2(const int* rowptr, const unsigned* csr, const int* cnt,
                        const bf16* zw2, const float* z1, const void* root2, const void* rb2,
                        const int* batch, float* gsum, const int* flag) {
  if (__builtin_amdgcn_readfirstlane(*flag))
    ragg2_body<true>(rowptr, csr, cnt, (const unsigned*)zw2, z1, root2, rb2, batch, gsum);
  else
    ragg2_body<false>(rowptr, csr, cnt, (const unsigned*)zw2, z1, root2, rb2, batch, gsum);
}

// ---- final ----
template<bool BF>
__device__ __forceinline__ void final_body(const unsigned* __restrict__ gmax,
                                           const float* __restrict__ gsum,
                                           const int* __restrict__ npg, const void* dw,
                                           const void* db, void* out) {
  int g = threadIdx.x;
  if (g >= N_GRAPH) return;
  float acc = ldf<BF>(db, 0);
  int np = npg[g]; if (np < 1) np = 1;
  float inv = 1.f / (float)np;
#pragma unroll
  for (int c = 0; c < 16; ++c) {
    acc += fdec(gmax[g * 16 + c]) * ldf<BF>(dw, c);
    acc += (gsum[g * 16 + c] * inv) * ldf<BF>(dw, 16 + c);
  }
  if (BF) ((bf16*)out)[g] = f2bf(acc);
  else ((float*)out)[g] = acc;
}
__global__ void k_final(const unsigned* gmax, const float* gsum, const int* npg,
                        const void* dw, const void* db, void* out, const int* flag) {
  if (__builtin_amdgcn_readfirstlane(*flag)) final_body<true>(gmax, gsum, npg, dw, db, out);
  else final_body<false>(gmax, gsum, npg, dw, db, out);
}

extern "C" void kernel_launch(void* const* d_in, const int* in_sizes, int n_in,
                              void* d_out, int out_size, void* d_ws, size_t ws_size,
                              hipStream_t stream) {
  const void* x        = d_in[0];
  const int*  ei       = (const int*)d_in[1];
  const int*  etype    = (const int*)d_in[2];
  const int*  batch    = (const int*)d_in[3];
  const void* gat_w    = d_in[4];
  const void* att_src  = d_in[5];
  const void* att_dst  = d_in[6];
  const void* gat_bias = d_in[7];
  const void* d1w      = d_in[8];
  const void* d1b      = d_in[9];
  const void* rw1      = d_in[10];
  const void* root1    = d_in[11];
  const void* rb1      = d_in[12];
  const void* rw2      = d_in[13];
  const void* root2    = d_in[14];
  const void* rb2      = d_in[15];
  const void* dw       = d_in[16];
  const void* db       = d_in[17];

  // ---- workspace layout (~129.2 MB) ----
  char* ws = (char*)d_ws;
  const size_t o_h     = 0;           // u16  N*128 (25.6MB)  — GAT table; zw2 overlays later
  const size_t o_plog  = 25600000;    // f32  E*4   (25.6MB)  — logits -> alpha in place
  const size_t o_xw1   = 51200000;    // bf16 R*N*32 (51.2MB) — RGCN1; dstarr aliases (dead first)
  const size_t o_dst   = 51200000;    // i32  E (6.4MB)       — dst per CSR pos (dead before xw1 writes)
  const size_t o_zw2   = 0;           // bf16 R*N*16 (25.6MB) — RGCN2, overlays h+plog (dead)
  const size_t o_asrc  = 102400000;   // f32 N*4 (1.6MB) -> m_arr
  const size_t o_adst  = 104000000;   // f32 N*4 (1.6MB) -> si_arr
  const size_t o_deg   = 105600000;   // i32 N (0.4MB)
  const size_t o_rowp  = 106000000;   // i32 N+1
  const size_t o_wp    = 106400016;   // i32 N
  const size_t o_cnt   = 106800016;   // i32 N*8 (3.2MB)
  const size_t o_csr   = 110000016;   // u32 E (6.4MB)
  const size_t o_z1    = 116400016;   // f32 N*32 (12.8MB)
  const size_t o_sblk  = 129200016;   // i32 NBLK_SCAN
  const size_t o_gmax  = 129201600;   // u32 G*16
  const size_t o_gsum  = 129217984;   // f32 G*16
  const size_t o_npg   = 129234368;   // i32 G
  const size_t o_flag  = 129235392;   // i32
  const size_t total   = 129235396;
  if (ws_size < total) return;

  u16*      h      = (u16*)(ws + o_h);
  float*    plog   = (float*)(ws + o_plog);
  bf16*     xw1    = (bf16*)(ws + o_xw1);
  int*      dstarr = (int*)(ws + o_dst);
  bf16*     zw2    = (bf16*)(ws + o_zw2);
  float*    a_src  = (float*)(ws + o_asrc);
  float*    a_dst  = (float*)(ws + o_adst);
  int*      deg    = (int*)(ws + o_deg);
  int*      rowptr = (int*)(ws + o_rowp);
  int*      wp     = (int*)(ws + o_wp);
  int*      cnt    = (int*)(ws + o_cnt);
  unsigned* csr    = (unsigned*)(ws + o_csr);
  float*    z1     = (float*)(ws + o_z1);
  int*      sblk   = (int*)(ws + o_sblk);
  unsigned* gmax   = (unsigned*)(ws + o_gmax);
  float*    gsum   = (float*)(ws + o_gsum);
  int*      npg    = (int*)(ws + o_npg);
  int*      flag   = (int*)(ws + o_flag);

  // dtype probe
  k_probe<<<1, 256, 0, stream>>>((const u16*)x, flag);

  // zero-init: deg..cnt contiguous, and gmax/gsum/npg
  hipMemsetAsync(ws + o_deg, 0, o_csr - o_deg, stream);
  hipMemsetAsync(ws + o_gmax, 0, 33792, stream);

  // merged: node transform + logits (blocks < N) + edge histogram (rest)
  k_gath_hist<<<N_NODES + 12500, 128, 0, stream>>>(x, gat_w, att_src, att_dst, h, a_src, a_dst,
                                                   ei, etype, deg, cnt, flag);

  // CSR scan + scatter
  k_scan_a<<<NBLK_SCAN, 256, 0, stream>>>(deg, rowptr, sblk);
  k_scan_b<<<1, 512, 0, stream>>>(sblk);
  k_scan_c<<<NBLK_SCAN, 256, 0, stream>>>(rowptr, wp, sblk);
  k_scatter<<<(N_EDGES + 255) / 256, 256, 0, stream>>>(ei, etype, a_src, a_dst, wp, csr,
                                                       (float4*)plog, dstarr);

  // softmax stats + alpha in place
  k_msum<<<N_NODES / 16, 256, 0, stream>>>(rowptr, plog, a_src, a_dst);
  k_alpha<<<(N_EDGES + 255) / 256, 256, 0, stream>>>(dstarr, a_src, a_dst, (float4*)plog);

  // merged: GAT aggregate (latency-bound) + RGCN1 transform (BW-bound) — overlap
  k_aggxw1<<<25000 + 100000, 256, 0, stream>>>(rowptr, csr, plog, h, gat_bias, d1w, d1b,
                                               batch, gmax, npg, x, rw1, xw1, flag);

  // RGCN1 gather
  k_ragg1<<<N_NODES / 4, 256, 0, stream>>>(rowptr, csr, cnt, xw1, x, root1, rb1, z1, flag);

  // RGCN2 (zw2 overlays h+plog — GAT phase done)
  k_zw2<<<dim3((N_NODES + 15) / 16, N_REL), 256, 0, stream>>>(z1, rw2, zw2, flag);
  k_ragg2<<<N_NODES / 4, 256, 0, stream>>>(rowptr, csr, cnt, zw2, z1, root2, rb2,
                                           batch, gsum, flag);

  // fuse
  k_final<<<1, 256, 0, stream>>>(gmax, gsum, npg, dw, db, d_out, flag);
}